// Round 10
// baseline (129.921 us; speedup 1.0000x reference)
//
#include <hip/hip_runtime.h>
#include <hip/hip_bf16.h>

#define NE    16
#define INF   512
#define OUTF  512
#define NT    2048
#define OTILE 32
#define TCH   64          // tokens per chunk (4 token-subtiles x 16)
#define REPS  5           // DIAGNOSTIC: repeat whole body to separate fixed floor vs marginal work

typedef __attribute__((ext_vector_type(4))) float f32x4;
typedef __attribute__((ext_vector_type(8))) short bf16x8;

__device__ inline short f2bf(float f) {
    union { __hip_bfloat16 h; short s; } u;
    u.h = __float2bfloat16(f);
    return u.s;
}

__device__ inline bf16x8 cvt8(f32x4 lo, f32x4 hi) {
    bf16x8 r;
    r[0] = f2bf(lo[0]); r[1] = f2bf(lo[1]);
    r[2] = f2bf(lo[2]); r[3] = f2bf(lo[3]);
    r[4] = f2bf(hi[0]); r[5] = f2bf(hi[1]);
    r[6] = f2bf(hi[2]); r[7] = f2bf(hi[3]);
    return r;
}

__global__ __launch_bounds__(512, 2)
void switch_linear_kernel(const float* __restrict__ x,
                          const int* __restrict__ idx,
                          const float* __restrict__ W,
                          const float* __restrict__ bias,
                          float* __restrict__ out)
{
    __shared__ int s_list[NT + TCH];
    __shared__ int s_wcnt[8];

    const int b   = blockIdx.x;
    const int e   = b & 15;              // expert; blocks of e sit on XCD e%8
    const int o0  = (b >> 4) * OTILE;    // out-tile base
    const int tid = threadIdx.x;
    const int lane = tid & 63;
    const int wid  = tid >> 6;           // 0..7

    // ---- Wave layout: 8 waves = 4 (token) x 2 (out) sub-tiles of 16 ----
    const int wt = wid >> 1;   // token sub-tile 0..3
    const int wo = wid & 1;    // out   sub-tile 0..1
    const int lr = lane & 15;  // fragment row/col
    const int q  = lane >> 4;  // quarter (k-group / acc row group)
    const int orow = o0 + wo * 16 + lr;

    for (int rep = 0; rep < REPS; ++rep) {
        // Compiler-opaque zero: forces genuine re-execution of all loads each rep
        int z = 0;
        asm volatile("" : "+v"(z));
        const float* xp = x + z;
        const int*   ip = idx + z;
        const float* Wp = W + z;
        const float* bp = bias + z;

        __syncthreads();  // protect s_list/s_wcnt reuse across reps

        // ---- Phase A: issue idx loads FIRST (latency hides under W hoist) ----
        int iv[4];
#pragma unroll
        for (int it = 0; it < 4; ++it)
            iv[it] = ip[wid * 256 + it * 64 + lane];

        // ---- Phase B: hoist B fragments (W rows, f32 -> bf16) into registers ----
        const float* wrow = Wp + ((size_t)e * OUTF + orow) * INF;
        bf16x8 bfr[16];
#pragma unroll
        for (int kk = 0; kk < 16; ++kk) {
            const float* p = wrow + kk * 32 + q * 8;
            f32x4 lo = *(const f32x4*)p;
            f32x4 hi = *(const f32x4*)(p + 4);
            bfr[kk] = cvt8(lo, hi);
        }
        const float bv = bp[e * OUTF + orow];

        // ---- Phase C: ballot-compaction token list (no atomics, deterministic) ----
        unsigned long long masks[4];
        int wtot = 0;
#pragma unroll
        for (int it = 0; it < 4; ++it) {
            const unsigned long long mk = __ballot(iv[it] == e);
            masks[it] = mk;
            wtot += __popcll(mk);
        }
        if (lane == 0) s_wcnt[wid] = wtot;
        __syncthreads();
        int base = 0;
#pragma unroll
        for (int w = 0; w < 8; ++w) { int c = s_wcnt[w]; if (w < wid) base += c; }
        const int cnt = s_wcnt[0] + s_wcnt[1] + s_wcnt[2] + s_wcnt[3]
                      + s_wcnt[4] + s_wcnt[5] + s_wcnt[6] + s_wcnt[7];
        const unsigned long long below = (1ull << lane) - 1ull;
        int run = base;
#pragma unroll
        for (int it = 0; it < 4; ++it) {
            const unsigned long long mk = masks[it];
            if (mk & (1ull << lane))
                s_list[run + __popcll(mk & below)] = wid * 256 + it * 64 + lane;
            run += __popcll(mk);
        }
        const int cnt_pad = (cnt + TCH - 1) & ~(TCH - 1);
        for (int i = cnt + tid; i < cnt_pad; i += 512) s_list[i] = -1;
        __syncthreads();
        if (cnt == 0) continue;  // block-uniform

        // ---- Phase D: loop over 64-token chunks (typically 2 iterations) ----
        for (int cb = 0; cb < cnt_pad; cb += TCH) {
            const int tok_a = s_list[cb + wt * 16 + lr];
            const float* xrow = xp + (size_t)(tok_a < 0 ? 0 : tok_a) * INF;
            f32x4 acc = {0.f, 0.f, 0.f, 0.f};
#pragma unroll
            for (int kk = 0; kk < 16; ++kk) {
                const float* p = xrow + kk * 32 + q * 8;
                f32x4 lo = *(const f32x4*)p;
                f32x4 hi = *(const f32x4*)(p + 4);
                bf16x8 afr = cvt8(lo, hi);
                acc = __builtin_amdgcn_mfma_f32_16x16x32_bf16(afr, bfr[kk], acc, 0, 0, 0);
            }
#pragma unroll
            for (int j = 0; j < 4; ++j) {
                const int tok = s_list[cb + wt * 16 + q * 4 + j];
                if (tok >= 0) out[(size_t)tok * OUTF + orow] = acc[j] + bv;
            }
        }
    }
}

extern "C" void kernel_launch(void* const* d_in, const int* in_sizes, int n_in,
                              void* d_out, int out_size, void* d_ws, size_t ws_size,
                              hipStream_t stream) {
    const float* x    = (const float*)d_in[0];
    const int*   idx  = (const int*)d_in[1];
    const float* W    = (const float*)d_in[2];
    const float* bias = (const float*)d_in[3];
    float* out = (float*)d_out;

    dim3 grid(NE * (OUTF / OTILE));  // 256 blocks: b&15 = expert, b>>4 = out-tile
    dim3 block(512);                 // 8 waves
    switch_linear_kernel<<<grid, block, 0, stream>>>(x, idx, W, bias, out);
}

// Round 11
// 30.781 us; speedup vs baseline: 4.2208x; 4.2208x over previous
//
#include <hip/hip_runtime.h>
#include <hip/hip_bf16.h>

#define NE    16
#define INF   512
#define OUTF  512
#define NT    2048
#define OTILE 32
#define TCH   64          // tokens per chunk (4 token-subtiles x 16)

typedef __attribute__((ext_vector_type(4))) float f32x4;
typedef __attribute__((ext_vector_type(8))) short bf16x8;

__device__ inline short f2bf(float f) {
    union { __hip_bfloat16 h; short s; } u;
    u.h = __float2bfloat16(f);
    return u.s;
}

__device__ inline bf16x8 cvt8(f32x4 lo, f32x4 hi) {
    bf16x8 r;
    r[0] = f2bf(lo[0]); r[1] = f2bf(lo[1]);
    r[2] = f2bf(lo[2]); r[3] = f2bf(lo[3]);
    r[4] = f2bf(hi[0]); r[5] = f2bf(hi[1]);
    r[6] = f2bf(hi[2]); r[7] = f2bf(hi[3]);
    return r;
}

__global__ __launch_bounds__(512, 2)
void switch_linear_kernel(const float* __restrict__ x,
                          const int* __restrict__ idx,
                          const float* __restrict__ W,
                          const float* __restrict__ bias,
                          float* __restrict__ out)
{
    __shared__ int s_list[NT + TCH];
    __shared__ int s_wcnt[8];

    const int b   = blockIdx.x;
    const int e   = b & 15;              // expert; blocks of e sit on XCD e%8
    const int o0  = (b >> 4) * OTILE;    // out-tile base
    const int tid = threadIdx.x;
    const int lane = tid & 63;
    const int wid  = tid >> 6;           // 0..7

    // ---- Phase A: issue idx loads FIRST (latency hides under W hoist) ----
    int iv[4];
#pragma unroll
    for (int it = 0; it < 4; ++it)
        iv[it] = idx[wid * 256 + it * 64 + lane];

    // ---- Wave layout: 8 waves = 4 (token) x 2 (out) sub-tiles of 16 ----
    const int wt = wid >> 1;   // token sub-tile 0..3
    const int wo = wid & 1;    // out   sub-tile 0..1
    const int lr = lane & 15;  // fragment row/col
    const int q  = lane >> 4;  // quarter (k-group / acc row group)

    // ---- Phase B: W-row hoist — ALL 32 loads issued before any convert ----
    // B-operand: lane holds col = lane&15 (out row of W), k = q*8 + j
    const int orow = o0 + wo * 16 + lr;
    const float* wrow = W + ((size_t)e * OUTF + orow) * INF;
    const float bv = bias[e * OUTF + orow];
    f32x4 wa[16], wb[16];
#pragma unroll
    for (int kk = 0; kk < 16; ++kk) {
        const float* p = wrow + kk * 32 + q * 8;
        wa[kk] = *(const f32x4*)p;
        wb[kk] = *(const f32x4*)(p + 4);
    }
    bf16x8 bfr[16];
#pragma unroll
    for (int kk = 0; kk < 16; ++kk)
        bfr[kk] = cvt8(wa[kk], wb[kk]);

    // ---- Phase C: ballot-compaction token list (no atomics, deterministic) ----
    unsigned long long masks[4];
    int wtot = 0;
#pragma unroll
    for (int it = 0; it < 4; ++it) {
        const unsigned long long mk = __ballot(iv[it] == e);
        masks[it] = mk;
        wtot += __popcll(mk);
    }
    if (lane == 0) s_wcnt[wid] = wtot;
    __syncthreads();
    int base = 0;
#pragma unroll
    for (int w = 0; w < 8; ++w) { int c = s_wcnt[w]; if (w < wid) base += c; }
    const int cnt = s_wcnt[0] + s_wcnt[1] + s_wcnt[2] + s_wcnt[3]
                  + s_wcnt[4] + s_wcnt[5] + s_wcnt[6] + s_wcnt[7];
    const unsigned long long below = (1ull << lane) - 1ull;
    int run = base;
#pragma unroll
    for (int it = 0; it < 4; ++it) {
        const unsigned long long mk = masks[it];
        if (mk & (1ull << lane))
            s_list[run + __popcll(mk & below)] = wid * 256 + it * 64 + lane;
        run += __popcll(mk);
    }
    const int cnt_pad = (cnt + TCH - 1) & ~(TCH - 1);
    for (int i = cnt + tid; i < cnt_pad; i += 512) s_list[i] = -1;
    __syncthreads();
    if (cnt == 0) return;

    // ---- Phase D: 64-token chunks; ALL 32 x-loads hoisted per chunk ----
    for (int cb = 0; cb < cnt_pad; cb += TCH) {
        const int tok_a = s_list[cb + wt * 16 + lr];
        const float* xrow = x + (size_t)(tok_a < 0 ? 0 : tok_a) * INF;
        f32x4 xa[16], xb[16];
#pragma unroll
        for (int kk = 0; kk < 16; ++kk) {
            const float* p = xrow + kk * 32 + q * 8;
            xa[kk] = *(const f32x4*)p;
            xb[kk] = *(const f32x4*)(p + 4);
        }
        f32x4 acc = {0.f, 0.f, 0.f, 0.f};
#pragma unroll
        for (int kk = 0; kk < 16; ++kk) {
            bf16x8 afr = cvt8(xa[kk], xb[kk]);
            acc = __builtin_amdgcn_mfma_f32_16x16x32_bf16(afr, bfr[kk], acc, 0, 0, 0);
        }
        // ---- Epilogue: D row = q*4+j (token), col = lr (out) ----
#pragma unroll
        for (int j = 0; j < 4; ++j) {
            const int tok = s_list[cb + wt * 16 + q * 4 + j];
            if (tok >= 0) out[(size_t)tok * OUTF + orow] = acc[j] + bv;
        }
    }
}

extern "C" void kernel_launch(void* const* d_in, const int* in_sizes, int n_in,
                              void* d_out, int out_size, void* d_ws, size_t ws_size,
                              hipStream_t stream) {
    const float* x    = (const float*)d_in[0];
    const int*   idx  = (const int*)d_in[1];
    const float* W    = (const float*)d_in[2];
    const float* bias = (const float*)d_in[3];
    float* out = (float*)d_out;

    dim3 grid(NE * (OUTF / OTILE));  // 256 blocks: b&15 = expert, b>>4 = out-tile
    dim3 block(512);                 // 8 waves -> 2 waves/SIMD at 1 block/CU
    switch_linear_kernel<<<grid, block, 0, stream>>>(x, idx, W, bias, out);
}

// Round 12
// 14.663 us; speedup vs baseline: 8.8607x; 2.0993x over previous
//
#include <hip/hip_runtime.h>
#include <hip/hip_bf16.h>

#define NE    16
#define INF   512
#define OUTF  512
#define NT    2048
#define OTILE 32
#define TCH   64          // tokens per chunk (4 token-subtiles x 16)
#define WROWS 32
#define LSTRIDE 520       // LDS row stride in bf16 elems (512 + 8 pad = 1040 B)

#define SZ_W   (WROWS * LSTRIDE * 2)            // 33280 B
#define SZ_X   (TCH * LSTRIDE * 2)              // 66560 B
#define SZ_LST ((NT + TCH) * 4)                 // 8448 B
#define SMEM_BYTES (SZ_W + SZ_X + SZ_LST + 32)  // ~108 KB

typedef __attribute__((ext_vector_type(4))) float f32x4;
typedef __attribute__((ext_vector_type(8))) short bf16x8;
typedef __attribute__((ext_vector_type(4))) short bf16x4;

__device__ inline short f2bf(float f) {
    union { __hip_bfloat16 h; short s; } u;
    u.h = __float2bfloat16(f);
    return u.s;
}

__device__ inline bf16x4 cvt4(f32x4 v) {
    bf16x4 r;
    r[0] = f2bf(v[0]); r[1] = f2bf(v[1]); r[2] = f2bf(v[2]); r[3] = f2bf(v[3]);
    return r;
}

__global__ __launch_bounds__(512, 2)
void switch_linear_kernel(const float* __restrict__ x,
                          const int* __restrict__ idx,
                          const float* __restrict__ W,
                          const float* __restrict__ bias,
                          float* __restrict__ out)
{
    extern __shared__ char smem[];
    short* s_W    = (short*)smem;                      // [WROWS][LSTRIDE] bf16
    short* s_X    = (short*)(smem + SZ_W);             // [TCH][LSTRIDE] bf16
    int*   s_list = (int*)(smem + SZ_W + SZ_X);        // token list
    int*   s_wcnt = (int*)(smem + SZ_W + SZ_X + SZ_LST);

    const int b   = blockIdx.x;
    const int e   = b & 15;              // expert; blocks of e sit on XCD e%8
    const int o0  = (b >> 4) * OTILE;    // out-tile base
    const int tid = threadIdx.x;
    const int lane = tid & 63;
    const int wid  = tid >> 6;           // 0..7

    // ---- Phase A: idx loads (registers) ----
    int iv[4];
#pragma unroll
    for (int it = 0; it < 4; ++it)
        iv[it] = idx[wid * 256 + it * 64 + lane];

    // ---- Phase B: stage W tile (contiguous 64 KB f32) -> LDS bf16, coalesced ----
    const float* wbase = W + ((size_t)e * OUTF + o0) * INF;  // 32 rows x 512, contiguous
#pragma unroll
    for (int i = 0; i < 8; ++i) {
        const int li = tid + i * 512;            // f32x4 index, 0..4095
        f32x4 v = ((const f32x4*)wbase)[li];
        const int fidx = li * 4;
        const int row = fidx >> 9;
        const int col = fidx & 511;
        *(bf16x4*)(&s_W[row * LSTRIDE + col]) = cvt4(v);
    }

    // ---- Phase C: ballot-compaction token list (no atomics, deterministic) ----
    unsigned long long masks[4];
    int wtot = 0;
#pragma unroll
    for (int it = 0; it < 4; ++it) {
        const unsigned long long mk = __ballot(iv[it] == e);
        masks[it] = mk;
        wtot += __popcll(mk);
    }
    if (lane == 0) s_wcnt[wid] = wtot;
    __syncthreads();                      // s_wcnt ready (s_W writes also done)
    int base = 0;
#pragma unroll
    for (int w = 0; w < 8; ++w) { int c = s_wcnt[w]; if (w < wid) base += c; }
    const int cnt = s_wcnt[0] + s_wcnt[1] + s_wcnt[2] + s_wcnt[3]
                  + s_wcnt[4] + s_wcnt[5] + s_wcnt[6] + s_wcnt[7];
    const unsigned long long below = (1ull << lane) - 1ull;
    int run = base;
#pragma unroll
    for (int it = 0; it < 4; ++it) {
        const unsigned long long mk = masks[it];
        if (mk & (1ull << lane))
            s_list[run + __popcll(mk & below)] = wid * 256 + it * 64 + lane;
        run += __popcll(mk);
    }
    const int cnt_pad = (cnt + TCH - 1) & ~(TCH - 1);
    for (int i = cnt + tid; i < cnt_pad; i += 512) s_list[i] = -1;
    __syncthreads();                      // s_list + s_W ready
    if (cnt == 0) return;                 // block-uniform

    // ---- Wave layout: 8 waves = 4 (token) x 2 (out) sub-tiles of 16 ----
    const int wt = wid >> 1;   // token sub-tile 0..3
    const int wo = wid & 1;    // out   sub-tile 0..1
    const int lr = lane & 15;  // fragment row/col
    const int q  = lane >> 4;  // quarter (k-group / acc row group)
    const int orow = o0 + wo * 16 + lr;

    // ---- W fragments from LDS (b128 reads, bank-spread by +16B pad) ----
    bf16x8 bfr[16];
#pragma unroll
    for (int kk = 0; kk < 16; ++kk)
        bfr[kk] = *(const bf16x8*)(&s_W[(wo * 16 + lr) * LSTRIDE + kk * 32 + q * 8]);
    const float bv = bias[e * OUTF + orow];

    // x-staging thread mapping: 8 threads per token row
    const int slot = tid >> 3;            // 0..63
    const int sub  = tid & 7;

    // ---- Phase D: 64-token chunks; stage x coalesced -> LDS -> fragments ----
    for (int cb = 0; cb < cnt_pad; cb += TCH) {
        // stage: each row read 128 B-contiguous per instruction by its 8 threads
        int tok_s = s_list[cb + slot];
        if (tok_s < 0) tok_s = 0;
        const f32x4* xr = (const f32x4*)(x + (size_t)tok_s * INF);
#pragma unroll
        for (int i = 0; i < 16; ++i) {
            f32x4 v = xr[sub + i * 8];
            *(bf16x4*)(&s_X[slot * LSTRIDE + sub * 4 + i * 32]) = cvt4(v);
        }
        __syncthreads();                  // s_X ready

        f32x4 acc = {0.f, 0.f, 0.f, 0.f};
#pragma unroll
        for (int kk = 0; kk < 16; ++kk) {
            bf16x8 afr = *(const bf16x8*)(&s_X[(wt * 16 + lr) * LSTRIDE + kk * 32 + q * 8]);
            acc = __builtin_amdgcn_mfma_f32_16x16x32_bf16(afr, bfr[kk], acc, 0, 0, 0);
        }
        // ---- Epilogue: D row = q*4+j (token), col = lr (out) ----
#pragma unroll
        for (int j = 0; j < 4; ++j) {
            const int tok = s_list[cb + wt * 16 + q * 4 + j];
            if (tok >= 0) out[(size_t)tok * OUTF + orow] = acc[j] + bv;
        }
        __syncthreads();                  // all s_X reads done before next stage
    }
}

extern "C" void kernel_launch(void* const* d_in, const int* in_sizes, int n_in,
                              void* d_out, int out_size, void* d_ws, size_t ws_size,
                              hipStream_t stream) {
    const float* x    = (const float*)d_in[0];
    const int*   idx  = (const int*)d_in[1];
    const float* W    = (const float*)d_in[2];
    const float* bias = (const float*)d_in[3];
    float* out = (float*)d_out;

    dim3 grid(NE * (OUTF / OTILE));  // 256 blocks: b&15 = expert, b>>4 = out-tile
    dim3 block(512);                 // 8 waves
    switch_linear_kernel<<<grid, block, SMEM_BYTES, stream>>>(x, idx, W, bias, out);
}

// Round 13
// 14.113 us; speedup vs baseline: 9.2056x; 1.0389x over previous
//
#include <hip/hip_runtime.h>
#include <hip/hip_bf16.h>

#define NE    16
#define INF   512
#define OUTF  512
#define NT    2048
#define OTILE 64          // out-cols per block (4 o-subtiles of 16)
#define TCH   32          // tokens per chunk (2 t-subtiles of 16)
#define NZ    2           // token-chunk split across blocks
#define WROWS OTILE
#define LSTRIDE 520       // LDS row stride in bf16 elems (512 + 8 pad = 1040 B)

#define SZ_W   (WROWS * LSTRIDE * 2)            // 66560 B
#define SZ_X   (TCH * LSTRIDE * 2)              // 33280 B
#define SZ_LST ((NT + TCH) * 4)                 // 8320 B
#define SMEM_BYTES (SZ_W + SZ_X + SZ_LST + 32)  // ~108 KB

typedef __attribute__((ext_vector_type(4))) float f32x4;
typedef __attribute__((ext_vector_type(8))) short bf16x8;
typedef __attribute__((ext_vector_type(4))) short bf16x4;

__device__ inline short f2bf(float f) {
    union { __hip_bfloat16 h; short s; } u;
    u.h = __float2bfloat16(f);
    return u.s;
}

__device__ inline bf16x4 cvt4(f32x4 v) {
    bf16x4 r;
    r[0] = f2bf(v[0]); r[1] = f2bf(v[1]); r[2] = f2bf(v[2]); r[3] = f2bf(v[3]);
    return r;
}

__global__ __launch_bounds__(512, 2)
void switch_linear_kernel(const float* __restrict__ x,
                          const int* __restrict__ idx,
                          const float* __restrict__ W,
                          const float* __restrict__ bias,
                          float* __restrict__ out)
{
    extern __shared__ char smem[];
    short* s_W    = (short*)smem;                      // [WROWS][LSTRIDE] bf16
    short* s_X    = (short*)(smem + SZ_W);             // [TCH][LSTRIDE] bf16
    int*   s_list = (int*)(smem + SZ_W + SZ_X);        // token list
    int*   s_wcnt = (int*)(smem + SZ_W + SZ_X + SZ_LST);

    const int b   = blockIdx.x;
    const int e   = b & 15;               // expert; all blocks of e on XCD e%8
    const int o0  = ((b >> 4) & 7) * OTILE;  // out-tile base (0..448)
    const int z   = b >> 7;               // token-chunk phase 0..1
    const int tid = threadIdx.x;
    const int lane = tid & 63;
    const int wid  = tid >> 6;            // 0..7

    // ---- Phase A: idx loads (registers) ----
    int iv[4];
#pragma unroll
    for (int it = 0; it < 4; ++it)
        iv[it] = idx[wid * 256 + it * 64 + lane];

    // ---- Phase B: stage W tile (contiguous 128 KB f32) -> LDS bf16, coalesced ----
    const float* wbase = W + ((size_t)e * OUTF + o0) * INF;  // 64 rows x 512, contiguous
#pragma unroll
    for (int i = 0; i < 16; ++i) {
        const int li = tid + i * 512;            // f32x4 index, 0..8191
        f32x4 v = ((const f32x4*)wbase)[li];
        const int row = li >> 7;                 // li*4 >> 9
        const int col = (li * 4) & 511;
        *(bf16x4*)(&s_W[row * LSTRIDE + col]) = cvt4(v);
    }

    // ---- Phase C: ballot-compaction token list (no atomics, deterministic) ----
    unsigned long long masks[4];
    int wtot = 0;
#pragma unroll
    for (int it = 0; it < 4; ++it) {
        const unsigned long long mk = __ballot(iv[it] == e);
        masks[it] = mk;
        wtot += __popcll(mk);
    }
    if (lane == 0) s_wcnt[wid] = wtot;
    __syncthreads();                      // s_wcnt ready (s_W writes also done)
    int base = 0;
#pragma unroll
    for (int w = 0; w < 8; ++w) { int c = s_wcnt[w]; if (w < wid) base += c; }
    const int cnt = s_wcnt[0] + s_wcnt[1] + s_wcnt[2] + s_wcnt[3]
                  + s_wcnt[4] + s_wcnt[5] + s_wcnt[6] + s_wcnt[7];
    const unsigned long long below = (1ull << lane) - 1ull;
    int run = base;
#pragma unroll
    for (int it = 0; it < 4; ++it) {
        const unsigned long long mk = masks[it];
        if (mk & (1ull << lane))
            s_list[run + __popcll(mk & below)] = wid * 256 + it * 64 + lane;
        run += __popcll(mk);
    }
    const int cnt_pad = (cnt + TCH - 1) & ~(TCH - 1);
    for (int i = cnt + tid; i < cnt_pad; i += 512) s_list[i] = -1;
    __syncthreads();                      // s_list + s_W ready
    if (cnt == 0) return;                 // block-uniform

    // ---- Wave layout: 8 waves = 2 (token) x 4 (out) sub-tiles of 16 ----
    const int wt = wid >> 2;   // token sub-tile 0..1
    const int wo = wid & 3;    // out   sub-tile 0..3
    const int lr = lane & 15;  // fragment row/col
    const int q  = lane >> 4;  // quarter (k-group / acc row group)
    const int orow = o0 + wo * 16 + lr;

    // ---- W fragments from LDS (b128 reads, bank-spread by +16B pad) ----
    bf16x8 bfr[16];
#pragma unroll
    for (int kk = 0; kk < 16; ++kk)
        bfr[kk] = *(const bf16x8*)(&s_W[(wo * 16 + lr) * LSTRIDE + kk * 32 + q * 8]);
    const float bv = bias[e * OUTF + orow];

    // x-staging thread mapping: 16 threads per token row (32 rows)
    const int slot = tid >> 4;            // 0..31
    const int sub  = tid & 15;

    // ---- Phase D: this z-phase's 32-token chunks; stage x coalesced -> LDS ----
    for (int cb = z * TCH; cb < cnt_pad; cb += NZ * TCH) {
        int tok_s = s_list[cb + slot];
        if (tok_s < 0) tok_s = 0;
        const f32x4* xr = (const f32x4*)(x + (size_t)tok_s * INF);
#pragma unroll
        for (int i = 0; i < 8; ++i) {
            f32x4 v = xr[sub + i * 16];
            *(bf16x4*)(&s_X[slot * LSTRIDE + sub * 4 + i * 64]) = cvt4(v);
        }
        __syncthreads();                  // s_X ready

        f32x4 acc = {0.f, 0.f, 0.f, 0.f};
#pragma unroll
        for (int kk = 0; kk < 16; ++kk) {
            bf16x8 afr = *(const bf16x8*)(&s_X[(wt * 16 + lr) * LSTRIDE + kk * 32 + q * 8]);
            acc = __builtin_amdgcn_mfma_f32_16x16x32_bf16(afr, bfr[kk], acc, 0, 0, 0);
        }
        // ---- Epilogue: D row = q*4+j (token), col = lr (out) ----
#pragma unroll
        for (int j = 0; j < 4; ++j) {
            const int tok = s_list[cb + wt * 16 + q * 4 + j];
            if (tok >= 0) out[(size_t)tok * OUTF + orow] = acc[j] + bv;
        }
        __syncthreads();                  // all s_X reads done before next stage
    }
}

extern "C" void kernel_launch(void* const* d_in, const int* in_sizes, int n_in,
                              void* d_out, int out_size, void* d_ws, size_t ws_size,
                              hipStream_t stream) {
    const float* x    = (const float*)d_in[0];
    const int*   idx  = (const int*)d_in[1];
    const float* W    = (const float*)d_in[2];
    const float* bias = (const float*)d_in[3];
    float* out = (float*)d_out;

    dim3 grid(NE * (OUTF / OTILE) * NZ);  // 16 x 8 x 2 = 256 blocks
    dim3 block(512);                      // 8 waves
    switch_linear_kernel<<<grid, block, SMEM_BYTES, stream>>>(x, idx, W, bias, out);
}